// Round 1
// baseline (668.614 us; speedup 1.0000x reference)
//
#include <hip/hip_runtime.h>

// minGRU log-space scan == linear recurrence h_t = exp(lc[t-1])*h_{t-1} + exp(lv[t]).
// One thread per (b,h) channel; sequential over T with double-buffered register
// tiles of U timesteps so ~64 global loads stay in flight per wave.
// B*H = 16384 channels = 256 waves -> 64-thread blocks, 256 blocks, ~1/CU.

constexpr int Bdim = 16;
constexpr int Tdim = 4096;
constexpr int Hdim = 1024;
constexpr int U    = 32;            // timesteps per register tile
constexpr int NBLK = Tdim / U;      // 128 tiles (even, so 2x-unrolled dbuf loop is exact)

__global__ __launch_bounds__(64)
void mingru_scan(const float* __restrict__ lc,   // (B, T, H)
                 const float* __restrict__ lv,   // (B, T+1, H)
                 float* __restrict__ out) {      // (B, T, H)
  const int chan = blockIdx.x * 64 + threadIdx.x;     // 0..16383
  const int b = chan >> 10;                            // /Hdim
  const int h = chan & (Hdim - 1);

  const float* lcp = lc  + (size_t)b * Tdim       * Hdim + h;
  const float* lvp = lv  + (size_t)b * (Tdim + 1) * Hdim + h;
  float*       op  = out + (size_t)b * Tdim       * Hdim + h;

  float state = __expf(lvp[0]);   // h_0

  float c0[U], v0[U], c1[U], v1[U];

  auto load = [&](float* cb, float* vb, int blk) {
    const float* pc = lcp + (size_t)blk * U * Hdim;
    const float* pv = lvp + ((size_t)blk * U + 1) * Hdim;
#pragma unroll
    for (int u = 0; u < U; ++u) {
      cb[u] = pc[(size_t)u * Hdim];
      vb[u] = pv[(size_t)u * Hdim];
    }
  };

  auto compute = [&](const float* cb, const float* vb, int blk) {
    float* po = op + (size_t)blk * U * Hdim;
#pragma unroll
    for (int u = 0; u < U; ++u) {
      const float c = __expf(cb[u]);
      const float v = __expf(vb[u]);
      state = __builtin_fmaf(c, state, v);   // h_{t+1} = c*h_t + v
      po[(size_t)u * Hdim] = state;
    }
  };

  load(c0, v0, 0);
  for (int ib = 0; ib < NBLK; ib += 2) {
    load(c1, v1, ib + 1);          // prefetch tile ib+1 while computing ib
    compute(c0, v0, ib);
    if (ib + 2 < NBLK) load(c0, v0, ib + 2);
    compute(c1, v1, ib + 1);
  }
}

extern "C" void kernel_launch(void* const* d_in, const int* in_sizes, int n_in,
                              void* d_out, int out_size, void* d_ws, size_t ws_size,
                              hipStream_t stream) {
  const float* lc  = (const float*)d_in[0];
  const float* lv  = (const float*)d_in[1];
  float*       out = (float*)d_out;

  const int nchan = Bdim * Hdim;           // 16384
  dim3 grid(nchan / 64), block(64);
  hipLaunchKernelGGL(mingru_scan, grid, block, 0, stream, lc, lv, out);
}

// Round 2
// 602.537 us; speedup vs baseline: 1.1097x; 1.1097x over previous
//
#include <hip/hip_runtime.h>

// minGRU scan: h_t = exp(lc[t-1]) * h_{t-1} + exp(lv[t]);  out = h_1..h_T.
// One thread per (b,h) channel (16384 channels = 256 waves, ~1 wave/CU).
// Latency-bound regime: the wave's own outstanding-load depth IS the BW.
// Design: register double-buffer of U=32 timesteps; next-tile loads are
// manually interleaved 1:1 with the current tile's fma chain so every load
// has a uniform prefetch distance of U steps. __launch_bounds__(64,1) frees
// the register budget (only 1 wave/SIMD possible anyway).

constexpr int Bdim = 16;
constexpr int Tdim = 4096;
constexpr int Hdim = 1024;
constexpr int U    = 32;           // timesteps per register tile
constexpr int NBLK = Tdim / U;     // 128 (even)

__global__ __launch_bounds__(64, 1)
void mingru_scan(const float* __restrict__ lc,   // (B, T, H)
                 const float* __restrict__ lv,   // (B, T+1, H)
                 float* __restrict__ out) {      // (B, T, H)
  const int chan = blockIdx.x * 64 + threadIdx.x;   // 0..16383
  const int b = chan >> 10;                          // / Hdim
  const int h = chan & (Hdim - 1);

  const float* lcp = lc  + (size_t)b * Tdim       * Hdim + h;
  const float* lvp = lv  + (size_t)b * (Tdim + 1) * Hdim + h;
  float*       op  = out + (size_t)b * Tdim       * Hdim + h;

  float state = __expf(lvp[0]);   // h_0

  float cA[U], vA[U], cB[U], vB[U];

  // Prologue: load tile 0 into A.
#pragma unroll
  for (int u = 0; u < U; ++u) {
    cA[u] = lcp[(size_t)u * Hdim];
    vA[u] = lvp[(size_t)(u + 1) * Hdim];
  }

  // Compute tile `ibc` from (cc,cv) while loading tile ibc+1 into (nc,nv),
  // loads interleaved 1:1 with the serial fma chain.
  auto tile_lc = [&](float (&cc)[U], float (&cv)[U],
                     float (&nc)[U], float (&nv)[U], int ibc) {
    const float* pc = lcp + ((size_t)(ibc + 1) * U) * Hdim;
    const float* pv = lvp + ((size_t)(ibc + 1) * U + 1) * Hdim;
    float*       po = op  + ((size_t)ibc * U) * Hdim;
#pragma unroll
    for (int u = 0; u < U; ++u) {
      nc[u] = pc[(size_t)u * Hdim];
      nv[u] = pv[(size_t)u * Hdim];
      state = __builtin_fmaf(__expf(cc[u]), state, __expf(cv[u]));
      po[(size_t)u * Hdim] = state;
    }
  };

  auto tile_c = [&](float (&cc)[U], float (&cv)[U], int ibc) {
    float* po = op + ((size_t)ibc * U) * Hdim;
#pragma unroll
    for (int u = 0; u < U; ++u) {
      state = __builtin_fmaf(__expf(cc[u]), state, __expf(cv[u]));
      po[(size_t)u * Hdim] = state;
    }
  };

  // Main loop: tiles 0..NBLK-3 (ping-pong A/B).
  for (int ib = 0; ib < NBLK - 2; ib += 2) {
    tile_lc(cA, vA, cB, vB, ib);       // compute ib, load ib+1 -> B
    tile_lc(cB, vB, cA, vA, ib + 1);   // compute ib+1, load ib+2 -> A
  }
  // Epilogue: compute NBLK-2 (loading NBLK-1 -> B), then NBLK-1.
  tile_lc(cA, vA, cB, vB, NBLK - 2);
  tile_c(cB, vB, NBLK - 1);
}

extern "C" void kernel_launch(void* const* d_in, const int* in_sizes, int n_in,
                              void* d_out, int out_size, void* d_ws, size_t ws_size,
                              hipStream_t stream) {
  const float* lc  = (const float*)d_in[0];
  const float* lv  = (const float*)d_in[1];
  float*       out = (float*)d_out;

  const int nchan = Bdim * Hdim;          // 16384
  dim3 grid(nchan / 64), block(64);
  hipLaunchKernelGGL(mingru_scan, grid, block, 0, stream, lc, lv, out);
}